// Round 5
// baseline (49.435 us; speedup 1.0000x reference)
//
#include <hip/hip_runtime.h>
#include <math.h>

constexpr int Bn = 64, Sn = 6, Tn = 2000, Cn = 25;
constexpr int COLS = Sn * Tn;              // 12000
constexpr int ROWS = Bn * Sn * Tn;         // 768000
constexpr int BDIM = 256;
constexpr int WV   = 4;                    // waves per block

// ---- fret geometry: wave-independent, 2 tiles of 64 rows per wave ----
constexpr int TPW   = 2;                   // tiles per wave
constexpr int TROWS = 64;                  // rows per tile (1 row per lane)
constexpr int TF4   = TROWS * Cn / 4;      // 400 float4 per tile
constexpr int RPBLK = WV * TPW * TROWS;    // 512 rows per block
constexpr int FBLK  = ROWS / RPBLK;        // 1500 fret blocks (exact)
constexpr int FPAD  = 1536;

// ---- onset geometry: 64 cols per block, wave w covers batch [16w,16w+16) ----
constexpr int OCOLS = 64;
constexpr int OBLK  = (COLS + OCOLS - 1) / OCOLS;   // 188 onset blocks
constexpr int OPAD  = 192;
constexpr int GRID  = OBLK + FBLK;         // 1688

// Segmented (<=2 contiguous strings per wave) butterfly reduce + LDS add.
static __device__ __forceinline__ void seg_reduce_add(float* ls, int s, float v, int lane) {
    const int s0 = __shfl(s, 0, 64);
    const int s1 = __shfl(s, 63, 64);
    if (s0 == s1) {                         // wave-uniform branch
        float a = v;
        #pragma unroll
        for (int off = 32; off; off >>= 1) a += __shfl_xor(a, off, 64);
        if (lane == 0) atomicAdd(&ls[s0], a);
    } else {
        float a = (s == s0) ? v : 0.0f;
        float b = (s == s0) ? 0.0f : v;
        #pragma unroll
        for (int off = 32; off; off >>= 1) {
            a += __shfl_xor(a, off, 64);
            b += __shfl_xor(b, off, 64);
        }
        if (lane == 0) { atomicAdd(&ls[s0], a); atomicAdd(&ls[s1], b); }
    }
}

__global__ __launch_bounds__(BDIM) void main_kernel(const float4* __restrict__ x4,
                                                    const int*    __restrict__ tgt,
                                                    const float*  __restrict__ ox,
                                                    const float*  __restrict__ ot,
                                                    float* __restrict__ pf,
                                                    float* __restrict__ po) {
    __shared__ float4 sbuf4[WV * TF4];     // 25.6 KB: wave w owns [w*TF4, +400)
    __shared__ float  ws[WV][Sn];          // per-wave string partials
    const int tid  = threadIdx.x;
    const int lane = tid & 63;
    const int w    = tid >> 6;
    if (lane < Sn) ws[w][lane] = 0.0f;     // same-wave LDS ordering: no barrier

    if (blockIdx.x < OBLK) {
        // ============ onset path: softmax over B, batch-split across waves ============
        const int cb  = blockIdx.x;
        const int col = cb * OCOLS + lane;           // wave-local column
        float4* ob4 = sbuf4;                          // reuse fret buffer: [4][64] float4
        float M = -INFINITY, S = 0.0f, ts = 0.0f, txs = 0.0f;
        if (col < COLS) {
            const int b0 = w * 16;
            #pragma unroll
            for (int h = 0; h < 2; ++h) {             // two 8-batch chunks (reg pressure)
                float xv[8], tv[8];
                #pragma unroll
                for (int k = 0; k < 8; ++k) xv[k] = ox[(b0 + h * 8 + k) * COLS + col];
                #pragma unroll
                for (int k = 0; k < 8; ++k) tv[k] = ot[(b0 + h * 8 + k) * COLS + col];
                float cm = -INFINITY;
                #pragma unroll
                for (int k = 0; k < 8; ++k) cm = fmaxf(cm, xv[k]);
                float cs = 0.0f;
                #pragma unroll
                for (int k = 0; k < 8; ++k) cs += __expf(xv[k] - cm);
                const float nm = fmaxf(M, cm);
                S = S * __expf(M - nm) + cs * __expf(cm - nm);   // exp(-inf)=0 first iter
                M = nm;
                #pragma unroll
                for (int k = 0; k < 8; ++k) { ts += tv[k]; txs += tv[k] * xv[k]; }
            }
        }
        ob4[w * OCOLS + lane] = make_float4(M, S, ts, txs);   // per-wave partial
        __syncthreads();
        if (tid < OCOLS) {                            // wave 0 merges the 4 partials
            float on = 0.0f;
            int   s  = Sn - 1;
            const int c = cb * OCOLS + tid;
            if (c < COLS) {
                s = c / Tn;
                float4 p0 = ob4[0 * OCOLS + tid];
                float Mm = p0.x, Sm = p0.y, tsm = p0.z, txm = p0.w;
                #pragma unroll
                for (int q = 1; q < WV; ++q) {
                    const float4 p = ob4[q * OCOLS + tid];
                    const float nm = fmaxf(Mm, p.x);
                    Sm  = Sm * __expf(Mm - nm) + p.y * __expf(p.x - nm);
                    Mm  = nm;
                    tsm += p.z; txm += p.w;
                }
                on = tsm * (Mm + __logf(Sm)) - txm;
            }
            seg_reduce_add(ws[0], s, on, tid);        // wave 0 only, same-wave DS order
            if (tid < Sn) po[tid * OPAD + cb] = ws[0][tid];
        }
    } else {
        // ============ fret path: wave-independent reg->LDS staged CE ============
        const int fb    = blockIdx.x - OBLK;
        const int wrow0 = fb * RPBLK + w * (TPW * TROWS);   // wave's first row
        const float4* gbase = x4 + (long)(wrow0 / 4) * Cn;  // = wrow0*25/4
        float4* b4 = sbuf4 + w * TF4;
        const float* bw = (const float*)b4;

        // Load BOTH tiles to registers up front: 14 coalesced float4 loads
        // (14 KB/wave in flight) + 2 coalesced target dwords.
        float4 rA[7], rB[7];
        const float4* gA = gbase + lane;
        const float4* gB = gbase + TF4 + lane;
        #pragma unroll
        for (int k = 0; k < 6; ++k) rA[k] = gA[k * 64];
        if (lane < 16) rA[6] = gA[384];
        #pragma unroll
        for (int k = 0; k < 6; ++k) rB[k] = gB[k * 64];
        if (lane < 16) rB[6] = gB[384];
        const int tcA = tgt[wrow0 + lane];
        const int tcB = tgt[wrow0 + TROWS + lane];

        // ---- tile A: stage to own LDS slice, compute CE (1 row/lane, stride 25) ----
        #pragma unroll
        for (int k = 0; k < 6; ++k) b4[k * 64 + lane] = rA[k];
        if (lane < 16) b4[384 + lane] = rA[6];
        {
            const float* rp = bw + lane * Cn;
            float m = -INFINITY, xt = 0.0f;
            #pragma unroll
            for (int c = 0; c < Cn; ++c) {
                const float e = rp[c];
                m  = fmaxf(m, e);
                xt = (c == tcA) ? e : xt;             // select: no runtime reg index
            }
            float ss = 0.0f;
            #pragma unroll
            for (int c = 0; c < Cn; ++c) ss += __expf(rp[c] - m);
            const float nll = m + __logf(ss) - xt;
            const int s = ((wrow0 + lane) / Tn) % Sn; // 64 consecutive rows: <=2 strings
            seg_reduce_add(ws[w], s, nll, lane);
        }
        // ---- tile B: same LDS slice (same-wave DS ops are in-order: WAR safe) ----
        #pragma unroll
        for (int k = 0; k < 6; ++k) b4[k * 64 + lane] = rB[k];
        if (lane < 16) b4[384 + lane] = rB[6];
        {
            const float* rp = bw + lane * Cn;
            float m = -INFINITY, xt = 0.0f;
            #pragma unroll
            for (int c = 0; c < Cn; ++c) {
                const float e = rp[c];
                m  = fmaxf(m, e);
                xt = (c == tcB) ? e : xt;
            }
            float ss = 0.0f;
            #pragma unroll
            for (int c = 0; c < Cn; ++c) ss += __expf(rp[c] - m);
            const float nll = m + __logf(ss) - xt;
            const int s = ((wrow0 + TROWS + lane) / Tn) % Sn;
            seg_reduce_add(ws[w], s, nll, lane);
        }
        __syncthreads();                              // once per block: combine 4 waves
        if (tid < Sn)
            pf[tid * FPAD + fb] = ws[0][tid] + ws[1][tid] + ws[2][tid] + ws[3][tid];
    }
}

__global__ __launch_bounds__(1024) void finish_kernel(const float* __restrict__ pf,
                                                      const float* __restrict__ po,
                                                      float* __restrict__ out) {
    __shared__ float acc[2 * Sn];
    const int tid  = threadIdx.x;
    const int lane = tid & 63;
    if (tid < 2 * Sn) acc[tid] = 0.0f;
    __syncthreads();

    // ---- fret partials: 6 coalesced strided sweeps over 1500 entries ----
    float fs[Sn];
    #pragma unroll
    for (int s = 0; s < Sn; ++s) {
        float v = 0.0f;
        for (int i = tid; i < FBLK; i += 1024) v += pf[s * FPAD + i];
        fs[s] = v;
    }
    #pragma unroll
    for (int off = 32; off; off >>= 1) {
        #pragma unroll
        for (int s = 0; s < Sn; ++s) fs[s] += __shfl_xor(fs[s], off, 64);
    }
    if (lane == 0) {
        #pragma unroll
        for (int s = 0; s < Sn; ++s) atomicAdd(&acc[s], fs[s]);
    }

    // ---- onset partials: wave w sums string w (188 entries) ----
    const int wv = tid >> 6;
    if (wv < Sn) {
        float v = 0.0f;
        for (int i = lane; i < OBLK; i += 64) v += po[wv * OPAD + i];
        #pragma unroll
        for (int off = 32; off; off >>= 1) v += __shfl_xor(v, off, 64);
        if (lane == 0) acc[Sn + wv] = v;
    }
    __syncthreads();

    if (tid == 0) {
        float fret = 0.0f, on = 0.0f, fsv[Sn], osv[Sn];
        #pragma unroll
        for (int s = 0; s < Sn; ++s) {
            fsv[s] = acc[s] * (1.0f / Bn);            // mean over batch
            osv[s] = acc[Sn + s];
            fret += fsv[s];
            on   += osv[s];
        }
        out[0] = 0.5f * fret + 0.5f * on;             // WEIGHT_FRET_ONSET = 0.5
        out[1] = fret;
        out[2] = on;
        #pragma unroll
        for (int s = 0; s < Sn; ++s) { out[3 + s] = fsv[s]; out[9 + s] = osv[s]; }
    }
}

extern "C" void kernel_launch(void* const* d_in, const int* in_sizes, int n_in,
                              void* d_out, int out_size, void* d_ws, size_t ws_size,
                              hipStream_t stream) {
    const float* output_fret  = (const float*)d_in[0];
    const int*   target_fret  = (const int*)d_in[1];
    const float* output_onset = (const float*)d_in[2];
    const float* target_onset = (const float*)d_in[3];
    float* pf  = (float*)d_ws;                 // [Sn][FPAD]
    float* po  = pf + Sn * FPAD;               // [Sn][OPAD]
    float* out = (float*)d_out;

    main_kernel<<<GRID, BDIM, 0, stream>>>((const float4*)output_fret, target_fret,
                                           output_onset, target_onset, pf, po);
    finish_kernel<<<1, 1024, 0, stream>>>(pf, po, out);
}

// Round 6
// 29.731 us; speedup vs baseline: 1.6627x; 1.6627x over previous
//
#include <hip/hip_runtime.h>
#include <math.h>

constexpr int Bn = 64, Sn = 6, Tn = 2000, Cn = 25;
constexpr int COLS = Sn * Tn;              // 12000
constexpr int ROWS = Bn * Sn * Tn;         // 768000
constexpr int BDIM = 256;
constexpr int WV   = 4;                    // waves per block

// ---- fret geometry: block-cooperative staging, 256 rows per block ----
constexpr int RPB  = 256;                  // rows per block (1 row per thread)
constexpr int TF4  = RPB * Cn / 4;         // 1600 float4 per block tile
constexpr int FBLK = ROWS / RPB;           // 3000 fret blocks (exact)
constexpr int FPAD = 3072;

// ---- onset geometry: 64 cols per block, wave w covers batch [16w,16w+16) ----
constexpr int OCOLS = 64;
constexpr int OBLK  = (COLS + OCOLS - 1) / OCOLS;   // 188 onset blocks
constexpr int OPAD  = 192;
constexpr int GRID  = OBLK + FBLK;         // 3188

// Segmented (<=2 contiguous strings per wave) butterfly reduce + LDS add.
static __device__ __forceinline__ void seg_reduce_add(float* ls, int s, float v, int lane) {
    const int s0 = __shfl(s, 0, 64);
    const int s1 = __shfl(s, 63, 64);
    if (s0 == s1) {                         // wave-uniform branch
        float a = v;
        #pragma unroll
        for (int off = 32; off; off >>= 1) a += __shfl_xor(a, off, 64);
        if (lane == 0) atomicAdd(&ls[s0], a);
    } else {
        float a = (s == s0) ? v : 0.0f;
        float b = (s == s0) ? 0.0f : v;
        #pragma unroll
        for (int off = 32; off; off >>= 1) {
            a += __shfl_xor(a, off, 64);
            b += __shfl_xor(b, off, 64);
        }
        if (lane == 0) { atomicAdd(&ls[s0], a); atomicAdd(&ls[s1], b); }
    }
}

__global__ __launch_bounds__(BDIM) void main_kernel(const float4* __restrict__ x4,
                                                    const int*    __restrict__ tgt,
                                                    const float*  __restrict__ ox,
                                                    const float*  __restrict__ ot,
                                                    float* __restrict__ pf,
                                                    float* __restrict__ po) {
    __shared__ float lds[RPB * Cn];        // 25.6 KB tile (fret) / partial buf (onset)
    __shared__ float ws[WV][Sn];           // per-wave string partials
    const int tid  = threadIdx.x;
    const int lane = tid & 63;
    const int w    = tid >> 6;
    if (lane < Sn) ws[w][lane] = 0.0f;     // same-wave LDS ordering: no barrier

    if (blockIdx.x < OBLK) {
        // ============ onset path: softmax over B, batch-split across waves ============
        const int cb  = blockIdx.x;
        const int col = cb * OCOLS + lane;            // wave-local column
        float4* ob4 = (float4*)lds;                   // [4][64] float4 partials
        float M = -INFINITY, S = 0.0f, ts = 0.0f, txs = 0.0f;
        if (col < COLS) {
            const int b0 = w * 16;
            #pragma unroll
            for (int h = 0; h < 2; ++h) {             // two 8-batch chunks (reg pressure)
                float xv[8], tv[8];
                #pragma unroll
                for (int k = 0; k < 8; ++k) xv[k] = ox[(b0 + h * 8 + k) * COLS + col];
                #pragma unroll
                for (int k = 0; k < 8; ++k) tv[k] = ot[(b0 + h * 8 + k) * COLS + col];
                float cm = -INFINITY;
                #pragma unroll
                for (int k = 0; k < 8; ++k) cm = fmaxf(cm, xv[k]);
                float cs = 0.0f;
                #pragma unroll
                for (int k = 0; k < 8; ++k) cs += __expf(xv[k] - cm);
                const float nm = fmaxf(M, cm);
                S = S * __expf(M - nm) + cs * __expf(cm - nm);   // exp(-inf)=0 first iter
                M = nm;
                #pragma unroll
                for (int k = 0; k < 8; ++k) { ts += tv[k]; txs += tv[k] * xv[k]; }
            }
        }
        ob4[w * OCOLS + lane] = make_float4(M, S, ts, txs);   // per-wave partial
        __syncthreads();
        if (tid < OCOLS) {                            // wave 0 merges the 4 partials
            float on = 0.0f;
            int   s  = Sn - 1;
            const int c = cb * OCOLS + tid;
            if (c < COLS) {
                s = c / Tn;
                float4 p0 = ob4[0 * OCOLS + tid];
                float Mm = p0.x, Sm = p0.y, tsm = p0.z, txm = p0.w;
                #pragma unroll
                for (int q = 1; q < WV; ++q) {
                    const float4 p = ob4[q * OCOLS + tid];
                    const float nm = fmaxf(Mm, p.x);
                    Sm  = Sm * __expf(Mm - nm) + p.y * __expf(p.x - nm);
                    Mm  = nm;
                    tsm += p.z; txm += p.w;
                }
                on = tsm * (Mm + __logf(Sm)) - txm;
            }
            seg_reduce_add(ws[0], s, on, tid);        // wave 0 only, same-wave DS order
            if (tid < Sn) po[tid * OPAD + cb] = ws[0][tid];
        }
    } else {
        // ===== fret path: block-cooperative staging (spill-free), 1 row/thread =====
        const int fb  = blockIdx.x - OBLK;
        const int row = fb * RPB + tid;
        const int tc  = tgt[row];                     // prefetched: overlaps staging
        // Direct global->LDS copy: <=7 float4 live at once, fully coalesced (1KB/instr).
        const float4* src = x4 + (long)fb * TF4;
        float4* lds4 = (float4*)lds;
        #pragma unroll
        for (int k = tid; k < TF4; k += BDIM) lds4[k] = src[k];
        __syncthreads();

        const float* rp = lds + tid * Cn;             // stride 25: conflict-free
        float m = -INFINITY, xt = 0.0f;
        #pragma unroll
        for (int c = 0; c < Cn; ++c) {
            const float e = rp[c];
            m  = fmaxf(m, e);
            xt = (c == tc) ? e : xt;                  // select: no runtime reg index
        }
        float ss = 0.0f;
        #pragma unroll
        for (int c = 0; c < Cn; ++c) ss += __expf(rp[c] - m);
        const float nll = m + __logf(ss) - xt;

        const int s = (row / Tn) % Sn;                // 64 consecutive rows: <=2 strings
        seg_reduce_add(ws[w], s, nll, lane);
        __syncthreads();
        if (tid < Sn)
            pf[tid * FPAD + fb] = ws[0][tid] + ws[1][tid] + ws[2][tid] + ws[3][tid];
    }
}

__global__ __launch_bounds__(1024) void finish_kernel(const float* __restrict__ pf,
                                                      const float* __restrict__ po,
                                                      float* __restrict__ out) {
    __shared__ float acc[2 * Sn];
    const int tid  = threadIdx.x;
    const int lane = tid & 63;
    if (tid < 2 * Sn) acc[tid] = 0.0f;
    __syncthreads();

    // ---- fret partials: 6 coalesced strided sweeps over 3000 entries ----
    float fs[Sn];
    #pragma unroll
    for (int s = 0; s < Sn; ++s) {
        float v = 0.0f;
        for (int i = tid; i < FBLK; i += 1024) v += pf[s * FPAD + i];
        fs[s] = v;
    }
    #pragma unroll
    for (int off = 32; off; off >>= 1) {
        #pragma unroll
        for (int s = 0; s < Sn; ++s) fs[s] += __shfl_xor(fs[s], off, 64);
    }
    if (lane == 0) {
        #pragma unroll
        for (int s = 0; s < Sn; ++s) atomicAdd(&acc[s], fs[s]);
    }

    // ---- onset partials: wave w sums string w (188 entries) ----
    const int wv = tid >> 6;
    if (wv < Sn) {
        float v = 0.0f;
        for (int i = lane; i < OBLK; i += 64) v += po[wv * OPAD + i];
        #pragma unroll
        for (int off = 32; off; off >>= 1) v += __shfl_xor(v, off, 64);
        if (lane == 0) acc[Sn + wv] = v;
    }
    __syncthreads();

    if (tid == 0) {
        float fret = 0.0f, on = 0.0f, fsv[Sn], osv[Sn];
        #pragma unroll
        for (int s = 0; s < Sn; ++s) {
            fsv[s] = acc[s] * (1.0f / Bn);            // mean over batch
            osv[s] = acc[Sn + s];
            fret += fsv[s];
            on   += osv[s];
        }
        out[0] = 0.5f * fret + 0.5f * on;             // WEIGHT_FRET_ONSET = 0.5
        out[1] = fret;
        out[2] = on;
        #pragma unroll
        for (int s = 0; s < Sn; ++s) { out[3 + s] = fsv[s]; out[9 + s] = osv[s]; }
    }
}

extern "C" void kernel_launch(void* const* d_in, const int* in_sizes, int n_in,
                              void* d_out, int out_size, void* d_ws, size_t ws_size,
                              hipStream_t stream) {
    const float* output_fret  = (const float*)d_in[0];
    const int*   target_fret  = (const int*)d_in[1];
    const float* output_onset = (const float*)d_in[2];
    const float* target_onset = (const float*)d_in[3];
    float* pf  = (float*)d_ws;                 // [Sn][FPAD]
    float* po  = pf + Sn * FPAD;               // [Sn][OPAD]
    float* out = (float*)d_out;

    main_kernel<<<GRID, BDIM, 0, stream>>>((const float4*)output_fret, target_fret,
                                           output_onset, target_onset, pf, po);
    finish_kernel<<<1, 1024, 0, stream>>>(pf, po, out);
}

// Round 7
// 25.945 us; speedup vs baseline: 1.9054x; 1.1459x over previous
//
#include <hip/hip_runtime.h>
#include <math.h>

constexpr int Bn = 64, Sn = 6, Tn = 2000, Cn = 25;
constexpr int COLS = Sn * Tn;              // 12000
constexpr int ROWS = Bn * Sn * Tn;         // 768000
constexpr int BDIM = 256;
constexpr int WV   = 4;                    // waves per block

// ---- fret: each wave autonomously pipelines NT tiles of 64 rows ----
constexpr int TROWS = 64;                  // rows per tile (1 per lane)
constexpr int TF4   = TROWS * Cn / 4;      // 400 float4 per tile
constexpr int NT    = 4;                   // tiles per wave (double-buffered)
constexpr int RPW   = NT * TROWS;          // 256 rows per wave
constexpr int RPB   = WV * RPW;            // 1024 rows per block
constexpr int FBLK  = ROWS / RPB;          // 750 fret blocks (exact)
constexpr int FPAD  = 768;

// ---- onset: 64 cols per block, wave w covers batch [16w,16w+16) (R6 verbatim) ----
constexpr int OCOLS = 64;
constexpr int OBLK  = (COLS + OCOLS - 1) / OCOLS;   // 188 onset blocks
constexpr int OPAD  = 192;
constexpr int GRID  = OBLK + FBLK;         // 938

typedef const __attribute__((address_space(1))) unsigned int guint;
typedef __attribute__((address_space(3)))       unsigned int luint;

// Segmented (<=2 contiguous strings per wave) butterfly reduce + LDS add.
static __device__ __forceinline__ void seg_reduce_add(float* ls, int s, float v, int lane) {
    const int s0 = __shfl(s, 0, 64);
    const int s1 = __shfl(s, 63, 64);
    if (s0 == s1) {                         // wave-uniform branch
        float a = v;
        #pragma unroll
        for (int off = 32; off; off >>= 1) a += __shfl_xor(a, off, 64);
        if (lane == 0) atomicAdd(&ls[s0], a);
    } else {
        float a = (s == s0) ? v : 0.0f;
        float b = (s == s0) ? 0.0f : v;
        #pragma unroll
        for (int off = 32; off; off >>= 1) {
            a += __shfl_xor(a, off, 64);
            b += __shfl_xor(b, off, 64);
        }
        if (lane == 0) { atomicAdd(&ls[s0], a); atomicAdd(&ls[s1], b); }
    }
}

__global__ __launch_bounds__(BDIM) void main_kernel(const float4* __restrict__ x4,
                                                    const int*    __restrict__ tgt,
                                                    const float*  __restrict__ ox,
                                                    const float*  __restrict__ ot,
                                                    float* __restrict__ pf,
                                                    float* __restrict__ po) {
    __shared__ float4 buf4[WV][2][TF4];    // 51.2 KB: wave-private double buffers
    __shared__ float  ws[WV][Sn];          // per-wave string partials
    const int tid  = threadIdx.x;
    const int lane = tid & 63;
    const int w    = tid >> 6;
    if (lane < Sn) ws[w][lane] = 0.0f;     // same-wave LDS ordering: no barrier

    if (blockIdx.x < OBLK) {
        // ============ onset path: softmax over B, batch-split across waves ============
        const int cb  = blockIdx.x;
        const int col = cb * OCOLS + lane;            // wave-local column
        float4* ob4 = &buf4[0][0][0];                 // reuse fret buffer: [4][64] float4
        float M = -INFINITY, S = 0.0f, ts = 0.0f, txs = 0.0f;
        if (col < COLS) {
            const int b0 = w * 16;
            #pragma unroll
            for (int h = 0; h < 2; ++h) {             // two 8-batch chunks (reg pressure)
                float xv[8], tv[8];
                #pragma unroll
                for (int k = 0; k < 8; ++k) xv[k] = ox[(b0 + h * 8 + k) * COLS + col];
                #pragma unroll
                for (int k = 0; k < 8; ++k) tv[k] = ot[(b0 + h * 8 + k) * COLS + col];
                float cm = -INFINITY;
                #pragma unroll
                for (int k = 0; k < 8; ++k) cm = fmaxf(cm, xv[k]);
                float cs = 0.0f;
                #pragma unroll
                for (int k = 0; k < 8; ++k) cs += __expf(xv[k] - cm);
                const float nm = fmaxf(M, cm);
                S = S * __expf(M - nm) + cs * __expf(cm - nm);   // exp(-inf)=0 first iter
                M = nm;
                #pragma unroll
                for (int k = 0; k < 8; ++k) { ts += tv[k]; txs += tv[k] * xv[k]; }
            }
        }
        ob4[w * OCOLS + lane] = make_float4(M, S, ts, txs);   // per-wave partial
        __syncthreads();
        if (tid < OCOLS) {                            // wave 0 merges the 4 partials
            float on = 0.0f;
            int   s  = Sn - 1;
            const int c = cb * OCOLS + tid;
            if (c < COLS) {
                s = c / Tn;
                float4 p0 = ob4[0 * OCOLS + tid];
                float Mm = p0.x, Sm = p0.y, tsm = p0.z, txm = p0.w;
                #pragma unroll
                for (int q = 1; q < WV; ++q) {
                    const float4 p = ob4[q * OCOLS + tid];
                    const float nm = fmaxf(Mm, p.x);
                    Sm  = Sm * __expf(Mm - nm) + p.y * __expf(p.x - nm);
                    Mm  = nm;
                    tsm += p.z; txm += p.w;
                }
                on = tsm * (Mm + __logf(Sm)) - txm;
            }
            seg_reduce_add(ws[0], s, on, tid);        // wave 0 only, same-wave DS order
            if (tid < Sn) po[tid * OPAD + cb] = ws[0][tid];
        }
    } else {
        // ===== fret path: wave-autonomous, double-buffered async pipeline =====
        const int fb    = blockIdx.x - OBLK;
        const int wrow0 = fb * RPB + w * RPW;         // wave's first row (mult of 4)
        const float4* gw = x4 + (long)(wrow0 / 4) * Cn;   // = wrow0*25/4
        float4* bb = &buf4[w][0][0];                  // [2][TF4] wave-private

        // All 4 targets upfront: 4 coalesced 256B dword loads (4 VGPR, static).
        int tcs[NT];
        #pragma unroll
        for (int t = 0; t < NT; ++t) tcs[t] = tgt[wrow0 + t * TROWS + lane];

        // stage(t): 7 x global_load_lds (6 full + 1 exec-masked), 1KB each.
        // LDS dest = wave-uniform base (+lane*16 by HW); global src per-lane.
        auto stage = [&](int t) {
            const int b = t & 1;
            const float4* gs = gw + (long)t * TF4 + lane;
            #pragma unroll
            for (int k = 0; k < 6; ++k)
                __builtin_amdgcn_global_load_lds((guint*)(gs + k * 64),
                                                 (luint*)(bb + b * TF4 + k * 64), 16, 0, 0);
            if (lane < 16)
                __builtin_amdgcn_global_load_lds((guint*)(gs + 384),
                                                 (luint*)(bb + b * TF4 + 384), 16, 0, 0);
        };

        auto compute = [&](int t) {
            const int b  = t & 1;
            const int tc = tcs[t];
            const float* rp = (const float*)(bb + b * TF4) + lane * Cn;  // stride 25
            float m = -INFINITY, xt = 0.0f;
            #pragma unroll
            for (int c = 0; c < Cn; ++c) {
                const float e = rp[c];
                m  = fmaxf(m, e);
                xt = (c == tc) ? e : xt;              // select: no runtime reg index
            }
            float ss = 0.0f;
            #pragma unroll
            for (int c = 0; c < Cn; ++c) ss += __expf(rp[c] - m);
            const float nll = m + __logf(ss) - xt;
            const int s = ((wrow0 + t * TROWS + lane) / Tn) % Sn;  // tile: <=2 strings
            seg_reduce_add(ws[w], s, nll, lane);
        };

        stage(0);
        stage(1);                                     // 14 loads + 4 tgt in flight
        #pragma unroll
        for (int t = 0; t < NT; ++t) {
            if (t < NT - 1)
                asm volatile("s_waitcnt vmcnt(7)" ::: "memory");   // tile t (+tgts) done; next tile flying
            else
                asm volatile("s_waitcnt vmcnt(0)" ::: "memory");   // final tile drain
            compute(t);
            if (t + 2 < NT) {
                asm volatile("s_waitcnt lgkmcnt(0)" ::: "memory"); // reads of buf[t&1] retired
                stage(t + 2);                                      // overwrite buffer t&1
            }
        }
        __syncthreads();                              // once per block: combine 4 waves
        if (tid < Sn)
            pf[tid * FPAD + fb] = ws[0][tid] + ws[1][tid] + ws[2][tid] + ws[3][tid];
    }
}

__global__ __launch_bounds__(1024) void finish_kernel(const float* __restrict__ pf,
                                                      const float* __restrict__ po,
                                                      float* __restrict__ out) {
    __shared__ float acc[2 * Sn];
    const int tid  = threadIdx.x;
    const int lane = tid & 63;
    if (tid < 2 * Sn) acc[tid] = 0.0f;
    __syncthreads();

    // ---- fret partials: 6 coalesced sweeps over 750 entries ----
    float fs[Sn];
    #pragma unroll
    for (int s = 0; s < Sn; ++s) {
        float v = 0.0f;
        for (int i = tid; i < FBLK; i += 1024) v += pf[s * FPAD + i];
        fs[s] = v;
    }
    #pragma unroll
    for (int off = 32; off; off >>= 1) {
        #pragma unroll
        for (int s = 0; s < Sn; ++s) fs[s] += __shfl_xor(fs[s], off, 64);
    }
    if (lane == 0) {
        #pragma unroll
        for (int s = 0; s < Sn; ++s) atomicAdd(&acc[s], fs[s]);
    }

    // ---- onset partials: wave w sums string w (188 entries) ----
    const int wv = tid >> 6;
    if (wv < Sn) {
        float v = 0.0f;
        for (int i = lane; i < OBLK; i += 64) v += po[wv * OPAD + i];
        #pragma unroll
        for (int off = 32; off; off >>= 1) v += __shfl_xor(v, off, 64);
        if (lane == 0) acc[Sn + wv] = v;
    }
    __syncthreads();

    if (tid == 0) {
        float fret = 0.0f, on = 0.0f, fsv[Sn], osv[Sn];
        #pragma unroll
        for (int s = 0; s < Sn; ++s) {
            fsv[s] = acc[s] * (1.0f / Bn);            // mean over batch
            osv[s] = acc[Sn + s];
            fret += fsv[s];
            on   += osv[s];
        }
        out[0] = 0.5f * fret + 0.5f * on;             // WEIGHT_FRET_ONSET = 0.5
        out[1] = fret;
        out[2] = on;
        #pragma unroll
        for (int s = 0; s < Sn; ++s) { out[3 + s] = fsv[s]; out[9 + s] = osv[s]; }
    }
}

extern "C" void kernel_launch(void* const* d_in, const int* in_sizes, int n_in,
                              void* d_out, int out_size, void* d_ws, size_t ws_size,
                              hipStream_t stream) {
    const float* output_fret  = (const float*)d_in[0];
    const int*   target_fret  = (const int*)d_in[1];
    const float* output_onset = (const float*)d_in[2];
    const float* target_onset = (const float*)d_in[3];
    float* pf  = (float*)d_ws;                 // [Sn][FPAD]
    float* po  = pf + Sn * FPAD;               // [Sn][OPAD]
    float* out = (float*)d_out;

    main_kernel<<<GRID, BDIM, 0, stream>>>((const float4*)output_fret, target_fret,
                                           output_onset, target_onset, pf, po);
    finish_kernel<<<1, 1024, 0, stream>>>(pf, po, out);
}